// Round 7
// baseline (393.476 us; speedup 1.0000x reference)
//
#include <hip/hip_runtime.h>

#define N_NODES 50000
#define NE 1000000
#define NBLK 196  // ceil(50000/256)

typedef float vfloat4 __attribute__((ext_vector_type(4)));

// ws layout (4-byte units), total ~6,050,260 = 24.2 MB (< 29 MB proven safe):
//   OFF  [N+1]    @ 0
//   SRT  [E ll]   @ 50004      (byte 200016, 8B aligned)
//   AX   [N*64]f  @ 2050004    (byte 8200016, 16B aligned)
//     HIST [N] aliases @ 2050004, CUR [N] aliases @ 2100004 (dead after sort;
//     gather passes fully overwrite AX before layer reads)
//   AE   [N*16]f  @ 5250004
//   BSUM [256]    @ 6050004
// Layer1 writes d_out; layer2 runs in-place on d_out.

__global__ __launch_bounds__(256) void hist_kernel(
    const int* __restrict__ ei, int* __restrict__ HIST) {
  int e = blockIdx.x * 256 + threadIdx.x;
  if (e >= NE) return;
  atomicAdd(&HIST[ei[NE + e]], 1);
}

__global__ __launch_bounds__(256) void scan_local(
    const int* __restrict__ HIST, int* __restrict__ OFF, int* __restrict__ BSUM) {
  __shared__ int s[256];
  int t = threadIdx.x;
  int g = blockIdx.x * 256 + t;
  int v = (g < N_NODES) ? HIST[g] : 0;
  s[t] = v;
  __syncthreads();
  #pragma unroll
  for (int off = 1; off < 256; off <<= 1) {
    int u = (t >= off) ? s[t - off] : 0;
    __syncthreads();
    s[t] += u;
    __syncthreads();
  }
  if (t == 255) BSUM[blockIdx.x] = s[255];
  if (g < N_NODES) OFF[g] = s[t] - v;
}

__global__ __launch_bounds__(256) void scan_bsums(
    int* __restrict__ BSUM, int* __restrict__ OFF) {
  __shared__ int s[256];
  int t = threadIdx.x;
  int v = (t < NBLK) ? BSUM[t] : 0;
  s[t] = v;
  __syncthreads();
  #pragma unroll
  for (int off = 1; off < 256; off <<= 1) {
    int u = (t >= off) ? s[t - off] : 0;
    __syncthreads();
    s[t] += u;
    __syncthreads();
  }
  if (t < NBLK) BSUM[t] = s[t] - v;
  if (t == 255) OFF[N_NODES] = s[255];
}

__global__ __launch_bounds__(256) void scan_add(
    int* __restrict__ OFF, const int* __restrict__ BSUM, int* __restrict__ CUR) {
  int g = blockIdx.x * 256 + threadIdx.x;
  if (g >= N_NODES) return;
  int o = OFF[g] + BSUM[blockIdx.x];
  OFF[g] = o;
  CUR[g] = o;
}

// NT store: 1M random 8B stores; bypassing L2 avoids cross-XCD partial-line
// ping-pong (R4 counters: 64 MB WRITE_SIZE for 8 MB of data).
__global__ __launch_bounds__(256) void sort_kernel(
    const int* __restrict__ ei, int* __restrict__ CUR, long long* __restrict__ SRT) {
  int e = blockIdx.x * 256 + threadIdx.x;
  if (e >= NE) return;
  int src = ei[e];
  int dst = ei[NE + e];
  int p = atomicAdd(&CUR[dst], 1);
  long long v = ((long long)e << 32) | (unsigned int)src;
  __builtin_nontemporal_store(v, &SRT[p]);
}

// One wave per node; lanes = 16 edge-slots x 4 quad-lanes (float4 each).
// Pass q reads the 64B quarter-row feat[src][q*16 .. q*16+15] per edge —
// per-pass random working set 3.2 MB < 4 MB per-XCD L2.
// HAS_EA (pass 0 of layer 1 only): also reads the full ea row (64B, NT —
// single-use 64 MB stream must not evict the x quarter) and produces AE.
template <bool HAS_EA>
__global__ __launch_bounds__(256) void gather_pass(
    const float* __restrict__ feat,  // [N,64]
    const float* __restrict__ ea,    // [E,16] or null
    const long long* __restrict__ SRT, const int* __restrict__ OFF,
    float* __restrict__ AGG,         // [N,64]
    float* __restrict__ AEout,       // [N,16] or null
    int q)
{
  int w = (blockIdx.x * 256 + threadIdx.x) >> 6;
  int lane = threadIdx.x & 63;
  if (w >= N_NODES) return;
  int s0 = OFF[w], s1 = OFF[w + 1];
  int slot = lane >> 2;  // 0..15
  int j = lane & 3;      // quad within row
  float ax0 = 0.f, ax1 = 0.f, ax2 = 0.f, ax3 = 0.f;
  float ae0 = 0.f, ae1 = 0.f, ae2 = 0.f, ae3 = 0.f;
  for (int p = s0 + slot; p < s1; p += 16) {
    long long se;
    if (HAS_EA) se = __builtin_nontemporal_load(&SRT[p]);
    else        se = SRT[p];
    int src = (int)(se & 0xffffffffLL);
    vfloat4 v = *(const vfloat4*)(feat + src * 64 + q * 16 + j * 4);
    ax0 += v[0]; ax1 += v[1]; ax2 += v[2]; ax3 += v[3];
    if (HAS_EA) {
      int eid = (int)(se >> 32);
      vfloat4 ev = __builtin_nontemporal_load((const vfloat4*)(ea + eid * 16 + j * 4));
      ae0 += ev[0]; ae1 += ev[1]; ae2 += ev[2]; ae3 += ev[3];
    }
  }
  // reduce across the 16 slots (mask bits 2..5); j bits preserved
  #pragma unroll
  for (int m = 4; m <= 32; m <<= 1) {
    ax0 += __shfl_xor(ax0, m, 64);
    ax1 += __shfl_xor(ax1, m, 64);
    ax2 += __shfl_xor(ax2, m, 64);
    ax3 += __shfl_xor(ax3, m, 64);
    if (HAS_EA) {
      ae0 += __shfl_xor(ae0, m, 64);
      ae1 += __shfl_xor(ae1, m, 64);
      ae2 += __shfl_xor(ae2, m, 64);
      ae3 += __shfl_xor(ae3, m, 64);
    }
  }
  if (lane < 4) {  // lane == j for slot 0
    vfloat4 o = {ax0, ax1, ax2, ax3};
    *(vfloat4*)(AGG + w * 64 + q * 16 + lane * 4) = o;
    if (HAS_EA) {
      vfloat4 oe = {ae0, ae1, ae2, ae3};
      *(vfloat4*)(AEout + w * 16 + lane * 4) = oe;
    }
  }
}

// out[i][:] = relu( x@Ws + bs + bn + ((AGG+x)@Wn_top + AE@Wn_bot)/(deg+1) )
// Safe in-place (out == xin): block stages its 64 rows in LDS before writing.
__global__ __launch_bounds__(256) void layer_kernel(
    const float* __restrict__ xin, const float* __restrict__ AGG,
    const float* __restrict__ AE, const int* __restrict__ OFF,
    const float* __restrict__ Ws, const float* __restrict__ bs,
    const float* __restrict__ Wn, const float* __restrict__ bn,
    float* __restrict__ out)
{
  __shared__ float Ml[144][68];
  __shared__ float Wl[72][64];
  __shared__ float biasl[64];
  __shared__ float invl[64];

  int t = threadIdx.x;
  int base = blockIdx.x * 64;

  if (t < 64) {
    int i = base + t;
    float deg = (i < N_NODES) ? (float)(OFF[i + 1] - OFF[i]) : 0.0f;
    invl[t] = 1.0f / (deg + 1.0f);
    biasl[t] = bs[t] + bn[t];
  }
  __syncthreads();

  for (int idx = t; idx < 4096; idx += 256) {
    int r = idx >> 6, k = idx & 63;
    int i = base + r;
    Ml[k][r] = (i < N_NODES) ? xin[i * 64 + k] : 0.0f;
  }
  for (int idx = t; idx < 4096; idx += 256) {
    int r = idx >> 6, k = idx & 63;
    int i = base + r;
    Ml[64 + k][r] = (i < N_NODES) ? (AGG[i * 64 + k] + xin[i * 64 + k]) * invl[r] : 0.0f;
  }
  for (int idx = t; idx < 1024; idx += 256) {
    int r = idx >> 4, k = idx & 15;
    int i = base + r;
    Ml[128 + k][r] = (i < N_NODES) ? AE[i * 16 + k] * invl[r] : 0.0f;
  }

  int tx = t & 15;
  int ty = t >> 4;
  float acc[4][4] = {{0.f}};

  for (int kc = 0; kc < 2; ++kc) {
    for (int idx = t; idx < 72 * 64; idx += 256) {
      int lr = idx >> 6, c = idx & 63;
      int k = kc * 72 + lr;
      Wl[lr][c] = (k < 64) ? Ws[k * 64 + c] : Wn[(k - 64) * 64 + c];
    }
    __syncthreads();
    #pragma unroll 8
    for (int k = 0; k < 72; ++k) {
      float4 a = *(const float4*)&Ml[kc * 72 + k][ty * 4];
      float4 b = *(const float4*)&Wl[k][tx * 4];
      float av[4] = {a.x, a.y, a.z, a.w};
      float bv[4] = {b.x, b.y, b.z, b.w};
      #pragma unroll
      for (int ri = 0; ri < 4; ++ri)
        #pragma unroll
        for (int ci = 0; ci < 4; ++ci)
          acc[ri][ci] = fmaf(av[ri], bv[ci], acc[ri][ci]);
    }
    __syncthreads();
  }

  #pragma unroll
  for (int ri = 0; ri < 4; ++ri) {
    int i = base + ty * 4 + ri;
    if (i < N_NODES) {
      float4 o;
      o.x = fmaxf(acc[ri][0] + biasl[tx * 4 + 0], 0.0f);
      o.y = fmaxf(acc[ri][1] + biasl[tx * 4 + 1], 0.0f);
      o.z = fmaxf(acc[ri][2] + biasl[tx * 4 + 2], 0.0f);
      o.w = fmaxf(acc[ri][3] + biasl[tx * 4 + 3], 0.0f);
      ((float4*)out)[i * 16 + tx] = o;
    }
  }
}

extern "C" void kernel_launch(void* const* d_in, const int* in_sizes, int n_in,
                              void* d_out, int out_size, void* d_ws, size_t ws_size,
                              hipStream_t stream) {
  const float* x   = (const float*)d_in[0];
  const int*   ei  = (const int*)d_in[1];
  const float* ea  = (const float*)d_in[2];
  const float* W1n = (const float*)d_in[3];
  const float* b1n = (const float*)d_in[4];
  const float* W1s = (const float*)d_in[5];
  const float* b1s = (const float*)d_in[6];
  const float* W2n = (const float*)d_in[7];
  const float* b2n = (const float*)d_in[8];
  const float* W2s = (const float*)d_in[9];
  const float* b2s = (const float*)d_in[10];

  int* wsi = (int*)d_ws;
  float* wsf = (float*)d_ws;
  int*  OFF  = wsi;                         // [0, 50001)
  long long* SRT = (long long*)(wsi + 50004);  // [50004, 2050004)
  float* AX  = wsf + 2050004;               // [2050004, 5250004)
  int*  HIST = wsi + 2050004;               // aliases AX (dead after sort)
  int*  CUR  = wsi + 2100004;               // aliases AX (dead after sort)
  float* AE  = wsf + 5250004;               // [5250004, 6050004)
  int*  BSUM = wsi + 6050004;               // [6050004, 6050260)
  float* out = (float*)d_out;

  hipMemsetAsync(HIST, 0, N_NODES * 4, stream);

  int eb = (NE + 255) / 256;
  hist_kernel<<<eb, 256, 0, stream>>>(ei, HIST);
  scan_local<<<NBLK, 256, 0, stream>>>(HIST, OFF, BSUM);
  scan_bsums<<<1, 256, 0, stream>>>(BSUM, OFF);
  scan_add<<<NBLK, 256, 0, stream>>>(OFF, BSUM, CUR);
  sort_kernel<<<eb, 256, 0, stream>>>(ei, CUR, SRT);

  int gb = 12500;  // 50000 nodes / 4 waves per block
  gather_pass<true><<<gb, 256, 0, stream>>>(x, ea, SRT, OFF, AX, AE, 0);
  gather_pass<false><<<gb, 256, 0, stream>>>(x, nullptr, SRT, OFF, AX, nullptr, 1);
  gather_pass<false><<<gb, 256, 0, stream>>>(x, nullptr, SRT, OFF, AX, nullptr, 2);
  gather_pass<false><<<gb, 256, 0, stream>>>(x, nullptr, SRT, OFF, AX, nullptr, 3);
  layer_kernel<<<782, 256, 0, stream>>>(x, AX, AE, OFF, W1s, b1s, W1n, b1n, out);
  gather_pass<false><<<gb, 256, 0, stream>>>(out, nullptr, SRT, OFF, AX, nullptr, 0);
  gather_pass<false><<<gb, 256, 0, stream>>>(out, nullptr, SRT, OFF, AX, nullptr, 1);
  gather_pass<false><<<gb, 256, 0, stream>>>(out, nullptr, SRT, OFF, AX, nullptr, 2);
  gather_pass<false><<<gb, 256, 0, stream>>>(out, nullptr, SRT, OFF, AX, nullptr, 3);
  layer_kernel<<<782, 256, 0, stream>>>(out, AX, AE, OFF, W2s, b2s, W2n, b2n, out);
}

// Round 8
// 237.854 us; speedup vs baseline: 1.6543x; 1.6543x over previous
//
#include <hip/hip_runtime.h>

#define N_NODES 50000
#define NE 1000000
#define NBLK 196     // ceil(N/256) scan blocks
#define NBUK 196     // buckets of 256 consecutive dst nodes
#define CHUNK 4096   // edges per bucket_scatter block

typedef float vfloat4 __attribute__((ext_vector_type(4)));
typedef unsigned short ushort4v __attribute__((ext_vector_type(4)));
typedef unsigned short ushort8v __attribute__((ext_vector_type(8)));

__device__ __forceinline__ unsigned short f2b(float f) {  // RNE f32->bf16
  unsigned u = __float_as_uint(f);
  u += 0x7FFF + ((u >> 16) & 1);
  return (unsigned short)(u >> 16);
}
__device__ __forceinline__ float b2f(unsigned short h) {
  return __uint_as_float(((unsigned)h) << 16);
}

// ws layout (4-byte units), end 6,450,260 = 25.8 MB (< 29 MB proven safe):
//   OFF  [N+1]     @ 0
//   SRT  [E ll]    @ 50004     (8B aligned)
//   XB   [N*64 bf] @ 2050004   (16B aligned; x-bf16, then h-bf16 after layer1)
//   AE   [N*16]f   @ 3650004
//   BCUR [256]     @ 4450004
//   BKT  [E ll]    @ 4450260   (8B aligned)
//     HIST [N]  aliases @ 4450260 (dead after scan, before BKT written)
//     BSUM [256] aliases @ 4500260
// AGG lives in d_out (scratch until layer2's final in-place overwrite).

__global__ __launch_bounds__(256) void hist_kernel(
    const int* __restrict__ ei, int* __restrict__ HIST) {
  int e = blockIdx.x * 256 + threadIdx.x;
  if (e >= NE) return;
  atomicAdd(&HIST[ei[NE + e]], 1);
}

__global__ __launch_bounds__(256) void scan_local(
    const int* __restrict__ HIST, int* __restrict__ OFF, int* __restrict__ BSUM) {
  __shared__ int s[256];
  int t = threadIdx.x;
  int g = blockIdx.x * 256 + t;
  int v = (g < N_NODES) ? HIST[g] : 0;
  s[t] = v;
  __syncthreads();
  #pragma unroll
  for (int off = 1; off < 256; off <<= 1) {
    int u = (t >= off) ? s[t - off] : 0;
    __syncthreads();
    s[t] += u;
    __syncthreads();
  }
  if (t == 255) BSUM[blockIdx.x] = s[255];
  if (g < N_NODES) OFF[g] = s[t] - v;
}

__global__ __launch_bounds__(256) void scan_bsums(
    int* __restrict__ BSUM, int* __restrict__ OFF) {
  __shared__ int s[256];
  int t = threadIdx.x;
  int v = (t < NBLK) ? BSUM[t] : 0;
  s[t] = v;
  __syncthreads();
  #pragma unroll
  for (int off = 1; off < 256; off <<= 1) {
    int u = (t >= off) ? s[t - off] : 0;
    __syncthreads();
    s[t] += u;
    __syncthreads();
  }
  if (t < NBLK) BSUM[t] = s[t] - v;
  if (t == 255) OFF[N_NODES] = s[255];
}

__global__ __launch_bounds__(256) void scan_add(
    int* __restrict__ OFF, const int* __restrict__ BSUM) {
  int g = blockIdx.x * 256 + threadIdx.x;
  if (g >= N_NODES) return;
  OFF[g] += BSUM[blockIdx.x];
}

__global__ __launch_bounds__(256) void init_bcur(
    const int* __restrict__ OFF, int* __restrict__ BCUR) {
  int b = threadIdx.x;
  BCUR[b] = OFF[min(b << 8, N_NODES)];
}

// Pass A: bin edges into NBUK contiguous-dst-range buckets.
// payload pack (45 bits): [eid:20 | src:17 | dst&255:8]
__global__ __launch_bounds__(256) void bucket_scatter(
    const int* __restrict__ ei, int* __restrict__ BCUR,
    long long* __restrict__ BKT) {
  __shared__ int cnt[256], sscan[256], base[256], cur[256], gb[256];
  __shared__ long long binned[CHUNK];
  __shared__ unsigned short dstl[CHUNK];
  int t = threadIdx.x;
  int c0 = blockIdx.x * CHUNK;
  int n = min(CHUNK, NE - c0);
  cnt[t] = 0;
  __syncthreads();
  for (int i = t; i < n; i += 256) {
    int dst = ei[NE + c0 + i];
    atomicAdd(&cnt[dst >> 8], 1);
  }
  __syncthreads();
  int myc = cnt[t];
  sscan[t] = myc;
  __syncthreads();
  #pragma unroll
  for (int off = 1; off < 256; off <<= 1) {
    int u = (t >= off) ? sscan[t - off] : 0;
    __syncthreads();
    sscan[t] += u;
    __syncthreads();
  }
  base[t] = sscan[t] - myc;
  cur[t] = sscan[t] - myc;
  if (myc > 0) gb[t] = atomicAdd(&BCUR[t], myc);
  __syncthreads();
  for (int i = t; i < n; i += 256) {
    int src = ei[c0 + i];
    int dst = ei[NE + c0 + i];
    int b = dst >> 8;
    int lp = atomicAdd(&cur[b], 1);
    binned[lp] = ((long long)(c0 + i) << 25) | ((long long)src << 8)
               | (long long)(dst & 255);
    dstl[lp] = (unsigned short)dst;
  }
  __syncthreads();
  // runs per bucket are contiguous in LDS and in BKT -> coalesced run writes
  for (int i = t; i < n; i += 256) {
    int b = ((int)dstl[i]) >> 8;
    BKT[gb[b] + (i - base[b])] = binned[i];
  }
}

// Pass B: one block per bucket; place entries at OFF[dst] positions.
// All writes land in this bucket's private contiguous SRT region (single
// writer block -> lines stay in one L2, written back once).
__global__ __launch_bounds__(1024) void bucket_sort(
    const long long* __restrict__ BKT, const int* __restrict__ OFF,
    long long* __restrict__ SRT) {
  __shared__ int lcur[256];
  int t = threadIdx.x;
  if (t < 256) lcur[t] = 0;
  __syncthreads();
  int b = blockIdx.x;
  int nb0 = b << 8;
  int nb1 = min(nb0 + 256, N_NODES);
  int s0 = OFF[nb0], s1 = OFF[nb1];
  for (int p = s0 + t; p < s1; p += 1024) {
    long long pl = BKT[p];
    int dl = (int)(pl & 255);
    int idx = atomicAdd(&lcur[dl], 1);
    SRT[OFF[nb0 + dl] + idx] = pl;
  }
}

__global__ __launch_bounds__(256) void conv_bf16(
    const float* __restrict__ in, unsigned short* __restrict__ out) {
  int i = blockIdx.x * 256 + threadIdx.x;  // one float4 per thread
  if (i >= (N_NODES * 64) / 4) return;
  vfloat4 v = ((const vfloat4*)in)[i];
  ushort4v o = { f2b(v[0]), f2b(v[1]), f2b(v[2]), f2b(v[3]) };
  ((ushort4v*)out)[i] = o;
}

// One wave per node; 8 edge-slots x 8 lanes; each lane reads ushort8 (16B)
// of the bf16 feature row (128B = 2 lines/edge vs 4 for f32).
template <bool HAS_EA>
__global__ __launch_bounds__(256) void gather_agg(
    const unsigned short* __restrict__ XB,  // [N,64] bf16
    const float* __restrict__ ea,           // [E,16] or null
    const long long* __restrict__ SRT, const int* __restrict__ OFF,
    float* __restrict__ AGG,                // [N,64] (d_out scratch)
    float* __restrict__ AEout)              // [N,16] or null
{
  int w = (blockIdx.x * 256 + threadIdx.x) >> 6;
  int lane = threadIdx.x & 63;
  if (w >= N_NODES) return;
  int s0 = OFF[w], s1 = OFF[w + 1];
  int slot = lane >> 3;   // 0..7
  int j = lane & 7;       // ushort8 chunk within row
  float ax[8] = {0.f,0.f,0.f,0.f,0.f,0.f,0.f,0.f};
  float ae0=0.f, ae1=0.f, ae2=0.f, ae3=0.f;
  for (int p = s0 + slot; p < s1; p += 8) {
    long long pl = SRT[p];
    int src = (int)((pl >> 8) & 0x1FFFF);
    ushort8v v = ((const ushort8v*)XB)[src * 8 + j];
    #pragma unroll
    for (int k = 0; k < 8; ++k) ax[k] += b2f(v[k]);
    if (HAS_EA) {
      int eid = (int)(pl >> 25);
      if (j < 4) {
        vfloat4 ev = *(const vfloat4*)(ea + eid * 16 + j * 4);
        ae0 += ev[0]; ae1 += ev[1]; ae2 += ev[2]; ae3 += ev[3];
      }
    }
  }
  #pragma unroll
  for (int m = 8; m <= 32; m <<= 1) {
    #pragma unroll
    for (int k = 0; k < 8; ++k) ax[k] += __shfl_xor(ax[k], m, 64);
    if (HAS_EA) {
      ae0 += __shfl_xor(ae0, m, 64);
      ae1 += __shfl_xor(ae1, m, 64);
      ae2 += __shfl_xor(ae2, m, 64);
      ae3 += __shfl_xor(ae3, m, 64);
    }
  }
  if (lane < 8) {
    vfloat4 o0 = {ax[0], ax[1], ax[2], ax[3]};
    vfloat4 o1 = {ax[4], ax[5], ax[6], ax[7]};
    *(vfloat4*)(AGG + w * 64 + lane * 8) = o0;
    *(vfloat4*)(AGG + w * 64 + lane * 8 + 4) = o1;
  }
  if (HAS_EA && lane < 4) {
    vfloat4 oe = {ae0, ae1, ae2, ae3};
    *(vfloat4*)(AEout + w * 16 + lane * 4) = oe;
  }
}

// out[i][:] = relu( x@Ws + bs + bn + ((AGG+x)@Wn_top + AE@Wn_bot)/(deg+1) )
// XBF: xin is bf16. OBF: out is bf16. In-place on AGG safe: block stages its
// own 64 rows into LDS before writing exactly those rows.
template <bool XBF, bool OBF>
__global__ __launch_bounds__(256) void layer_kernel(
    const void* __restrict__ xin_, const float* __restrict__ AGG,
    const float* __restrict__ AE, const int* __restrict__ OFF,
    const float* __restrict__ Ws, const float* __restrict__ bs,
    const float* __restrict__ Wn, const float* __restrict__ bn,
    void* __restrict__ out_)
{
  __shared__ float Ml[144][68];
  __shared__ float Wl[72][64];
  __shared__ float biasl[64];
  __shared__ float invl[64];

  const float* xf = (const float*)xin_;
  const unsigned short* xb = (const unsigned short*)xin_;

  int t = threadIdx.x;
  int base = blockIdx.x * 64;

  if (t < 64) {
    int i = base + t;
    float deg = (i < N_NODES) ? (float)(OFF[i + 1] - OFF[i]) : 0.0f;
    invl[t] = 1.0f / (deg + 1.0f);
    biasl[t] = bs[t] + bn[t];
  }
  __syncthreads();

  for (int idx = t; idx < 4096; idx += 256) {
    int r = idx >> 6, k = idx & 63;
    int i = base + r;
    float xv = 0.f, av = 0.f;
    if (i < N_NODES) {
      xv = XBF ? b2f(xb[i * 64 + k]) : xf[i * 64 + k];
      av = AGG[i * 64 + k];
    }
    Ml[k][r] = xv;
    Ml[64 + k][r] = (av + xv) * invl[r];
  }
  for (int idx = t; idx < 1024; idx += 256) {
    int r = idx >> 4, k = idx & 15;
    int i = base + r;
    Ml[128 + k][r] = (i < N_NODES) ? AE[i * 16 + k] * invl[r] : 0.0f;
  }

  int tx = t & 15;
  int ty = t >> 4;
  float acc[4][4] = {{0.f}};

  for (int kc = 0; kc < 2; ++kc) {
    for (int idx = t; idx < 72 * 64; idx += 256) {
      int lr = idx >> 6, c = idx & 63;
      int k = kc * 72 + lr;
      Wl[lr][c] = (k < 64) ? Ws[k * 64 + c] : Wn[(k - 64) * 64 + c];
    }
    __syncthreads();
    #pragma unroll 8
    for (int k = 0; k < 72; ++k) {
      float4 a = *(const float4*)&Ml[kc * 72 + k][ty * 4];
      float4 b = *(const float4*)&Wl[k][tx * 4];
      float av[4] = {a.x, a.y, a.z, a.w};
      float bv[4] = {b.x, b.y, b.z, b.w};
      #pragma unroll
      for (int ri = 0; ri < 4; ++ri)
        #pragma unroll
        for (int ci = 0; ci < 4; ++ci)
          acc[ri][ci] = fmaf(av[ri], bv[ci], acc[ri][ci]);
    }
    __syncthreads();
  }

  #pragma unroll
  for (int ri = 0; ri < 4; ++ri) {
    int i = base + ty * 4 + ri;
    if (i < N_NODES) {
      float o0 = fmaxf(acc[ri][0] + biasl[tx * 4 + 0], 0.0f);
      float o1 = fmaxf(acc[ri][1] + biasl[tx * 4 + 1], 0.0f);
      float o2 = fmaxf(acc[ri][2] + biasl[tx * 4 + 2], 0.0f);
      float o3 = fmaxf(acc[ri][3] + biasl[tx * 4 + 3], 0.0f);
      if (OBF) {
        ushort4v ob = { f2b(o0), f2b(o1), f2b(o2), f2b(o3) };
        ((ushort4v*)out_)[i * 16 + tx] = ob;
      } else {
        float4 of = {o0, o1, o2, o3};
        ((float4*)out_)[i * 16 + tx] = of;
      }
    }
  }
}

extern "C" void kernel_launch(void* const* d_in, const int* in_sizes, int n_in,
                              void* d_out, int out_size, void* d_ws, size_t ws_size,
                              hipStream_t stream) {
  const float* x   = (const float*)d_in[0];
  const int*   ei  = (const int*)d_in[1];
  const float* ea  = (const float*)d_in[2];
  const float* W1n = (const float*)d_in[3];
  const float* b1n = (const float*)d_in[4];
  const float* W1s = (const float*)d_in[5];
  const float* b1s = (const float*)d_in[6];
  const float* W2n = (const float*)d_in[7];
  const float* b2n = (const float*)d_in[8];
  const float* W2s = (const float*)d_in[9];
  const float* b2s = (const float*)d_in[10];

  int* wsi = (int*)d_ws;
  float* wsf = (float*)d_ws;
  int*  OFF  = wsi;                                   // [0, 50001)
  long long* SRT = (long long*)(wsi + 50004);         // 8 MB
  unsigned short* XB = (unsigned short*)(wsi + 2050004);  // 6.4 MB bf16
  float* AE  = wsf + 3650004;                         // 3.2 MB
  int*  BCUR = wsi + 4450004;                         // 1 KB
  long long* BKT = (long long*)(wsi + 4450260);       // 8 MB
  int*  HIST = wsi + 4450260;                         // alias BKT (dead early)
  int*  BSUM = wsi + 4500260;                         // alias BKT
  float* AGG = (float*)d_out;                         // scratch until layer2
  float* out = (float*)d_out;

  hipMemsetAsync(HIST, 0, N_NODES * 4, stream);

  hist_kernel<<<(NE + 255) / 256, 256, 0, stream>>>(ei, HIST);
  scan_local<<<NBLK, 256, 0, stream>>>(HIST, OFF, BSUM);
  scan_bsums<<<1, 256, 0, stream>>>(BSUM, OFF);
  scan_add<<<NBLK, 256, 0, stream>>>(OFF, BSUM);
  init_bcur<<<1, 256, 0, stream>>>(OFF, BCUR);
  bucket_scatter<<<(NE + CHUNK - 1) / CHUNK, 256, 0, stream>>>(ei, BCUR, BKT);
  bucket_sort<<<NBUK, 1024, 0, stream>>>(BKT, OFF, SRT);
  conv_bf16<<<(N_NODES * 64 / 4 + 255) / 256, 256, 0, stream>>>(x, XB);

  gather_agg<true><<<12500, 256, 0, stream>>>(XB, ea, SRT, OFF, AGG, AE);
  layer_kernel<false, true><<<782, 256, 0, stream>>>(
      x, AGG, AE, OFF, W1s, b1s, W1n, b1n, XB);   // h (bf16) overwrites XB
  gather_agg<false><<<12500, 256, 0, stream>>>(XB, nullptr, SRT, OFF, AGG, nullptr);
  layer_kernel<true, false><<<782, 256, 0, stream>>>(
      XB, AGG, AE, OFF, W2s, b2s, W2n, b2n, out); // in-place on d_out
}

// Round 9
// 217.040 us; speedup vs baseline: 1.8129x; 1.0959x over previous
//
#include <hip/hip_runtime.h>

#define N_NODES 50000
#define NE 1000000
#define NBUK 196     // buckets of 256 consecutive dst nodes
#define CHUNK 4096   // edges per bucket_scatter/count block
#define MAXBE 6144   // LDS edge-buffer capacity in bucket_sort (bucket avg 5102, +14 sigma)

typedef float vfloat4 __attribute__((ext_vector_type(4)));
typedef unsigned short ushort4v __attribute__((ext_vector_type(4)));
typedef unsigned short ushort8v __attribute__((ext_vector_type(8)));

__device__ __forceinline__ unsigned short f2b(float f) {  // RNE f32->bf16
  unsigned u = __float_as_uint(f);
  u += 0x7FFF + ((u >> 16) & 1);
  return (unsigned short)(u >> 16);
}
__device__ __forceinline__ float b2f(unsigned short h) {
  return __uint_as_float(((unsigned)h) << 16);
}

// ws layout (4-byte units), end 6,450,772 = 25.8 MB (< 29 MB proven safe):
//   OFF  [N+1]     @ 0
//   SRT  [E ll]    @ 50004     (8B aligned)
//   XB   [N*64 bf] @ 2050004   (x-bf16, then h-bf16 after layer1)
//   AE   [N*16]f   @ 3650004
//   BCNT [256]     @ 4450004
//   BOFF [256]     @ 4450260
//   BCUR [256]     @ 4450516
//   BKT  [E ll]    @ 4450772   (8B aligned)
// AGG lives in d_out (scratch until layer2's final in-place overwrite).

// payload pack (45 bits): [eid:20 | src:17 | dst&255:8]

__global__ __launch_bounds__(256) void bucket_count(
    const int* __restrict__ ei, int* __restrict__ BCNT) {
  __shared__ int c[256];
  int t = threadIdx.x;
  c[t] = 0;
  __syncthreads();
  int i0 = blockIdx.x * CHUNK;
  int n = min(CHUNK, NE - i0);
  for (int i = t; i < n; i += 256)
    atomicAdd(&c[ei[NE + i0 + i] >> 8], 1);
  __syncthreads();
  if (t < NBUK && c[t] > 0) atomicAdd(&BCNT[t], c[t]);
}

__global__ __launch_bounds__(256) void scan_buckets(
    const int* __restrict__ BCNT, int* __restrict__ BOFF,
    int* __restrict__ BCUR, int* __restrict__ OFF) {
  __shared__ int s[256];
  int t = threadIdx.x;
  int v = (t < NBUK) ? BCNT[t] : 0;
  s[t] = v;
  __syncthreads();
  #pragma unroll
  for (int off = 1; off < 256; off <<= 1) {
    int u = (t >= off) ? s[t - off] : 0;
    __syncthreads();
    s[t] += u;
    __syncthreads();
  }
  int ex = s[t] - v;
  if (t < NBUK) { BOFF[t] = ex; BCUR[t] = ex; }
  if (t == NBUK - 1) BOFF[NBUK] = s[t];  // = NE
  if (t == 0) OFF[N_NODES] = NE;
}

// Pass A: bin edges into NBUK contiguous-dst-range buckets (coalesced run writes).
__global__ __launch_bounds__(256) void bucket_scatter(
    const int* __restrict__ ei, int* __restrict__ BCUR,
    long long* __restrict__ BKT) {
  __shared__ int cnt[256], sscan[256], base[256], cur[256], gb[256];
  __shared__ long long binned[CHUNK];
  __shared__ unsigned short dstl[CHUNK];
  int t = threadIdx.x;
  int c0 = blockIdx.x * CHUNK;
  int n = min(CHUNK, NE - c0);
  cnt[t] = 0;
  __syncthreads();
  for (int i = t; i < n; i += 256) {
    int dst = ei[NE + c0 + i];
    atomicAdd(&cnt[dst >> 8], 1);
  }
  __syncthreads();
  int myc = cnt[t];
  sscan[t] = myc;
  __syncthreads();
  #pragma unroll
  for (int off = 1; off < 256; off <<= 1) {
    int u = (t >= off) ? sscan[t - off] : 0;
    __syncthreads();
    sscan[t] += u;
    __syncthreads();
  }
  base[t] = sscan[t] - myc;
  cur[t] = sscan[t] - myc;
  if (myc > 0) gb[t] = atomicAdd(&BCUR[t], myc);
  __syncthreads();
  for (int i = t; i < n; i += 256) {
    int src = ei[c0 + i];
    int dst = ei[NE + c0 + i];
    int b = dst >> 8;
    int lp = atomicAdd(&cur[b], 1);
    binned[lp] = ((long long)(c0 + i) << 25) | ((long long)src << 8)
               | (long long)(dst & 255);
    dstl[lp] = (unsigned short)dst;
  }
  __syncthreads();
  for (int i = t; i < n; i += 256) {
    int b = ((int)dstl[i]) >> 8;
    __builtin_nontemporal_store(binned[i], &BKT[gb[b] + (i - base[b])]);
  }
}

// Pass B: one block per bucket. Stage bucket edges in LDS, count per dst,
// local scan -> per-node OFF (replaces the old global hist+scan), then place
// into SRT at exact positions (writes stay in this bucket's private 40 KB).
__global__ __launch_bounds__(1024) void bucket_sort(
    const long long* __restrict__ BKT, const int* __restrict__ BOFF,
    int* __restrict__ OFF, long long* __restrict__ SRT) {
  __shared__ int cnt[256], ss[256], loff[256], cur[256];
  __shared__ long long buf[MAXBE];
  int t = threadIdx.x;
  if (t < 256) { cnt[t] = 0; cur[t] = 0; }
  __syncthreads();
  int b = blockIdx.x;
  int s0 = BOFF[b], s1 = BOFF[b + 1];
  int n = s1 - s0;
  for (int i = t; i < n; i += 1024) {
    long long pl = __builtin_nontemporal_load(&BKT[s0 + i]);
    if (i < MAXBE) buf[i] = pl;
    atomicAdd(&cnt[(int)(pl & 255)], 1);
  }
  __syncthreads();
  if (t < 256) ss[t] = cnt[t];
  __syncthreads();
  #pragma unroll
  for (int off = 1; off < 256; off <<= 1) {
    int u = 0;
    if (t < 256 && t >= off) u = ss[t - off];
    __syncthreads();
    if (t < 256) ss[t] += u;
    __syncthreads();
  }
  if (t < 256) loff[t] = ss[t] - cnt[t];
  __syncthreads();
  int nb0 = b << 8;
  if (t < 256 && nb0 + t < N_NODES) OFF[nb0 + t] = s0 + loff[t];
  for (int i = t; i < n; i += 1024) {
    long long pl = (i < MAXBE) ? buf[i] : __builtin_nontemporal_load(&BKT[s0 + i]);
    int dl = (int)(pl & 255);
    int p = atomicAdd(&cur[dl], 1);
    SRT[s0 + loff[dl] + p] = pl;
  }
}

__global__ __launch_bounds__(256) void conv_bf16(
    const float* __restrict__ in, unsigned short* __restrict__ out) {
  int i = blockIdx.x * 256 + threadIdx.x;  // one float4 per thread
  if (i >= (N_NODES * 64) / 4) return;
  vfloat4 v = ((const vfloat4*)in)[i];
  ushort4v o = { f2b(v[0]), f2b(v[1]), f2b(v[2]), f2b(v[3]) };
  ((ushort4v*)out)[i] = o;
}

// One wave per node; 8 edge-slots x 8 lanes; lane reads ushort8 (16B) of the
// bf16 row (128B = 2 lines/edge). Streams (SRT, ea, AGG/AE out) use NT
// hints so the 6.4 MB XB working set can stay resident in per-XCD L2.
template <bool HAS_EA>
__global__ __launch_bounds__(256) void gather_agg(
    const unsigned short* __restrict__ XB,  // [N,64] bf16
    const float* __restrict__ ea,           // [E,16] or null
    const long long* __restrict__ SRT, const int* __restrict__ OFF,
    float* __restrict__ AGG,                // [N,64] (d_out scratch)
    float* __restrict__ AEout)              // [N,16] or null
{
  int w = (blockIdx.x * 256 + threadIdx.x) >> 6;
  int lane = threadIdx.x & 63;
  if (w >= N_NODES) return;
  int s0 = OFF[w], s1 = OFF[w + 1];
  int slot = lane >> 3;   // 0..7
  int j = lane & 7;       // ushort8 chunk within row
  float ax[8] = {0.f,0.f,0.f,0.f,0.f,0.f,0.f,0.f};
  float ae0=0.f, ae1=0.f, ae2=0.f, ae3=0.f;
  for (int p = s0 + slot; p < s1; p += 8) {
    long long pl = __builtin_nontemporal_load(&SRT[p]);
    int src = (int)((pl >> 8) & 0x1FFFF);
    ushort8v v = ((const ushort8v*)XB)[src * 8 + j];
    #pragma unroll
    for (int k = 0; k < 8; ++k) ax[k] += b2f(v[k]);
    if (HAS_EA) {
      int eid = (int)(pl >> 25);
      if (j < 4) {
        vfloat4 ev = __builtin_nontemporal_load((const vfloat4*)(ea + eid * 16 + j * 4));
        ae0 += ev[0]; ae1 += ev[1]; ae2 += ev[2]; ae3 += ev[3];
      }
    }
  }
  #pragma unroll
  for (int m = 8; m <= 32; m <<= 1) {
    #pragma unroll
    for (int k = 0; k < 8; ++k) ax[k] += __shfl_xor(ax[k], m, 64);
    if (HAS_EA) {
      ae0 += __shfl_xor(ae0, m, 64);
      ae1 += __shfl_xor(ae1, m, 64);
      ae2 += __shfl_xor(ae2, m, 64);
      ae3 += __shfl_xor(ae3, m, 64);
    }
  }
  if (lane < 8) {
    vfloat4 o0 = {ax[0], ax[1], ax[2], ax[3]};
    vfloat4 o1 = {ax[4], ax[5], ax[6], ax[7]};
    __builtin_nontemporal_store(o0, (vfloat4*)(AGG + w * 64 + lane * 8));
    __builtin_nontemporal_store(o1, (vfloat4*)(AGG + w * 64 + lane * 8 + 4));
  }
  if (HAS_EA && lane < 4) {
    vfloat4 oe = {ae0, ae1, ae2, ae3};
    __builtin_nontemporal_store(oe, (vfloat4*)(AEout + w * 16 + lane * 4));
  }
}

// out[i][:] = relu( x@Ws + bs + bn + ((AGG+x)@Wn_top + AE@Wn_bot)/(deg+1) )
// XBF: xin is bf16. OBF: out is bf16. In-place on AGG safe: block stages its
// own 64 rows into LDS before writing exactly those rows.
template <bool XBF, bool OBF>
__global__ __launch_bounds__(256) void layer_kernel(
    const void* __restrict__ xin_, const float* __restrict__ AGG,
    const float* __restrict__ AE, const int* __restrict__ OFF,
    const float* __restrict__ Ws, const float* __restrict__ bs,
    const float* __restrict__ Wn, const float* __restrict__ bn,
    void* __restrict__ out_)
{
  __shared__ float Ml[144][68];
  __shared__ float Wl[72][64];
  __shared__ float biasl[64];
  __shared__ float invl[64];

  const float* xf = (const float*)xin_;
  const unsigned short* xb = (const unsigned short*)xin_;

  int t = threadIdx.x;
  int base = blockIdx.x * 64;

  if (t < 64) {
    int i = base + t;
    float deg = (i < N_NODES) ? (float)(OFF[i + 1] - OFF[i]) : 0.0f;
    invl[t] = 1.0f / (deg + 1.0f);
    biasl[t] = bs[t] + bn[t];
  }
  __syncthreads();

  for (int idx = t; idx < 4096; idx += 256) {
    int r = idx >> 6, k = idx & 63;
    int i = base + r;
    float xv = 0.f, av = 0.f;
    if (i < N_NODES) {
      xv = XBF ? b2f(xb[i * 64 + k]) : xf[i * 64 + k];
      av = AGG[i * 64 + k];
    }
    Ml[k][r] = xv;
    Ml[64 + k][r] = (av + xv) * invl[r];
  }
  for (int idx = t; idx < 1024; idx += 256) {
    int r = idx >> 4, k = idx & 15;
    int i = base + r;
    Ml[128 + k][r] = (i < N_NODES) ? AE[i * 16 + k] * invl[r] : 0.0f;
  }

  int tx = t & 15;
  int ty = t >> 4;
  float acc[4][4] = {{0.f}};

  for (int kc = 0; kc < 2; ++kc) {
    for (int idx = t; idx < 72 * 64; idx += 256) {
      int lr = idx >> 6, c = idx & 63;
      int k = kc * 72 + lr;
      Wl[lr][c] = (k < 64) ? Ws[k * 64 + c] : Wn[(k - 64) * 64 + c];
    }
    __syncthreads();
    #pragma unroll 8
    for (int k = 0; k < 72; ++k) {
      float4 a = *(const float4*)&Ml[kc * 72 + k][ty * 4];
      float4 b = *(const float4*)&Wl[k][tx * 4];
      float av[4] = {a.x, a.y, a.z, a.w};
      float bv[4] = {b.x, b.y, b.z, b.w};
      #pragma unroll
      for (int ri = 0; ri < 4; ++ri)
        #pragma unroll
        for (int ci = 0; ci < 4; ++ci)
          acc[ri][ci] = fmaf(av[ri], bv[ci], acc[ri][ci]);
    }
    __syncthreads();
  }

  #pragma unroll
  for (int ri = 0; ri < 4; ++ri) {
    int i = base + ty * 4 + ri;
    if (i < N_NODES) {
      float o0 = fmaxf(acc[ri][0] + biasl[tx * 4 + 0], 0.0f);
      float o1 = fmaxf(acc[ri][1] + biasl[tx * 4 + 1], 0.0f);
      float o2 = fmaxf(acc[ri][2] + biasl[tx * 4 + 2], 0.0f);
      float o3 = fmaxf(acc[ri][3] + biasl[tx * 4 + 3], 0.0f);
      if (OBF) {
        ushort4v ob = { f2b(o0), f2b(o1), f2b(o2), f2b(o3) };
        ((ushort4v*)out_)[i * 16 + tx] = ob;
      } else {
        float4 of = {o0, o1, o2, o3};
        ((float4*)out_)[i * 16 + tx] = of;
      }
    }
  }
}

extern "C" void kernel_launch(void* const* d_in, const int* in_sizes, int n_in,
                              void* d_out, int out_size, void* d_ws, size_t ws_size,
                              hipStream_t stream) {
  const float* x   = (const float*)d_in[0];
  const int*   ei  = (const int*)d_in[1];
  const float* ea  = (const float*)d_in[2];
  const float* W1n = (const float*)d_in[3];
  const float* b1n = (const float*)d_in[4];
  const float* W1s = (const float*)d_in[5];
  const float* b1s = (const float*)d_in[6];
  const float* W2n = (const float*)d_in[7];
  const float* b2n = (const float*)d_in[8];
  const float* W2s = (const float*)d_in[9];
  const float* b2s = (const float*)d_in[10];

  int* wsi = (int*)d_ws;
  float* wsf = (float*)d_ws;
  int*  OFF  = wsi;                                   // [0, 50001)
  long long* SRT = (long long*)(wsi + 50004);         // 8 MB
  unsigned short* XB = (unsigned short*)(wsi + 2050004);  // 6.4 MB bf16
  float* AE  = wsf + 3650004;                         // 3.2 MB
  int*  BCNT = wsi + 4450004;
  int*  BOFF = wsi + 4450260;
  int*  BCUR = wsi + 4450516;
  long long* BKT = (long long*)(wsi + 4450772);       // 8 MB
  float* AGG = (float*)d_out;                         // scratch until layer2
  float* out = (float*)d_out;

  hipMemsetAsync(BCNT, 0, 256 * 4, stream);

  int cb = (NE + CHUNK - 1) / CHUNK;  // 245
  bucket_count<<<cb, 256, 0, stream>>>(ei, BCNT);
  scan_buckets<<<1, 256, 0, stream>>>(BCNT, BOFF, BCUR, OFF);
  bucket_scatter<<<cb, 256, 0, stream>>>(ei, BCUR, BKT);
  bucket_sort<<<NBUK, 1024, 0, stream>>>(BKT, BOFF, OFF, SRT);
  conv_bf16<<<(N_NODES * 64 / 4 + 255) / 256, 256, 0, stream>>>(x, XB);

  gather_agg<true><<<12500, 256, 0, stream>>>(XB, ea, SRT, OFF, AGG, AE);
  layer_kernel<false, true><<<782, 256, 0, stream>>>(
      x, AGG, AE, OFF, W1s, b1s, W1n, b1n, XB);   // h (bf16) overwrites XB
  gather_agg<false><<<12500, 256, 0, stream>>>(XB, nullptr, SRT, OFF, AGG, nullptr);
  layer_kernel<true, false><<<782, 256, 0, stream>>>(
      XB, AGG, AE, OFF, W2s, b2s, W2n, b2n, out); // in-place on d_out
}